// Round 2
// baseline (256.518 us; speedup 1.0000x reference)
//
#include <hip/hip_runtime.h>

#define B_ 16
#define C_ 3
#define H_ 384
#define W_ 1280
#define HW_ (H_*W_)
#define EPS_ 1e-7f

__device__ __forceinline__ void mat3mul(const float* A, const float* Bm, float* C) {
  #pragma unroll
  for (int i = 0; i < 3; i++)
    #pragma unroll
    for (int j = 0; j < 3; j++)
      C[i*3+j] = A[i*3+0]*Bm[0*3+j] + A[i*3+1]*Bm[1*3+j] + A[i*3+2]*Bm[2*3+j];
}

// Compute M = K * R * inv(K)  (9 floats) and T = K * t (3 floats) for batch b.
__device__ void compute_MT(const float* __restrict__ pose,
                           const float* __restrict__ intr,
                           int b, float* M, float* T)
{
  float K[9];
  #pragma unroll
  for (int i = 0; i < 9; i++) K[i] = intr[b*9 + i];
  float aa0 = pose[b*6 + 0];
  float aa1 = pose[b*6 + 1];
  float aa2 = pose[b*6 + 2];
  float t0  = pose[b*6 + 3];
  float t1  = pose[b*6 + 4];
  float t2  = pose[b*6 + 5];

  // Rodrigues (matches reference rot_from_axisangle)
  float theta = sqrtf(aa0*aa0 + aa1*aa1 + aa2*aa2);
  float invn  = 1.0f / (theta + EPS_);
  float x = aa0*invn, y = aa1*invn, z = aa2*invn;
  float c = cosf(theta), s = sinf(theta), t = 1.0f - c;
  float R[9] = {
    t*x*x + c,   t*x*y - s*z, t*z*x + s*y,
    t*x*y + s*z, t*y*y + c,   t*y*z - s*x,
    t*z*x - s*y, t*y*z + s*x, t*z*z + c
  };

  // inv(K) via adjugate
  float a = K[0], bb = K[1], cc = K[2];
  float d = K[3], e  = K[4], f  = K[5];
  float g = K[6], h  = K[7], ii = K[8];
  float A0 = e*ii - f*h;
  float A1 = f*g  - d*ii;
  float A2 = d*h  - e*g;
  float det = a*A0 + bb*A1 + cc*A2;
  float id  = 1.0f / det;
  float iK[9] = {
    A0*id, (cc*h - bb*ii)*id, (bb*f - cc*e)*id,
    A1*id, (a*ii - cc*g)*id,  (cc*d - a*f)*id,
    A2*id, (bb*g - a*h)*id,   (a*e  - bb*d)*id
  };

  float KR[9];
  mat3mul(K, R, KR);
  mat3mul(KR, iK, M);
  T[0] = K[0]*t0 + K[1]*t1 + K[2]*t2;
  T[1] = K[3]*t0 + K[4]*t1 + K[5]*t2;
  T[2] = K[6]*t0 + K[7]*t1 + K[8]*t2;
}

__global__ void param_kernel(const float* __restrict__ pose,
                             const float* __restrict__ intr,
                             float* __restrict__ params)
{
  int b = threadIdx.x;
  if (b < B_) {
    float M[9], T[3];
    compute_MT(pose, intr, b, M, T);
    #pragma unroll
    for (int i = 0; i < 9; i++) params[b*12 + i] = M[i];
    #pragma unroll
    for (int i = 0; i < 3; i++) params[b*12 + 9 + i] = T[i];
  }
}

__global__ __launch_bounds__(256) void warp_kernel(
    const float* __restrict__ src,
    const float* __restrict__ depth,
    const float* __restrict__ params,
    const float* __restrict__ pose,
    const float* __restrict__ intr,
    float* __restrict__ out,
    int use_params)
{
  __shared__ float sp[12];
  int b = blockIdx.y;
  if (threadIdx.x == 0) {
    if (use_params) {
      #pragma unroll
      for (int i = 0; i < 12; i++) sp[i] = params[b*12 + i];
    } else {
      float M[9], T[3];
      compute_MT(pose, intr, b, M, T);
      #pragma unroll
      for (int i = 0; i < 9; i++) sp[i] = M[i];
      #pragma unroll
      for (int i = 0; i < 3; i++) sp[9 + i] = T[i];
    }
  }
  __syncthreads();
  float m00 = sp[0], m01 = sp[1], m02 = sp[2];
  float m10 = sp[3], m11 = sp[4], m12 = sp[5];
  float m20 = sp[6], m21 = sp[7], m22 = sp[8];
  float T0  = sp[9], T1  = sp[10], T2 = sp[11];

  int p = blockIdx.x * 256 + threadIdx.x;   // HW_ divisible by 256, no guard
  int j = p % W_;
  int i = p / W_;

  float d = depth[(size_t)b * HW_ + p];
  float xf = (float)j, yf = (float)i;

  float cx = (m00*xf + m01*yf + m02)*d + T0;
  float cy = (m10*xf + m11*yf + m12)*d + T1;
  float cz = (m20*xf + m21*yf + m22)*d + T2;
  float zz = cz + EPS_;
  float px = cx / zz;
  float py = cy / zz;

  float x0f = floorf(px), y0f = floorf(py);
  float x1f = x0f + 1.0f, y1f = y0f + 1.0f;
  float wx1 = px - x0f, wx0 = 1.0f - wx1;
  float wy1 = py - y0f, wy0 = 1.0f - wy1;

  float mx0 = (x0f >= 0.0f && x0f <= (float)(W_-1)) ? 1.0f : 0.0f;
  float mx1 = (x1f >= 0.0f && x1f <= (float)(W_-1)) ? 1.0f : 0.0f;
  float my0 = (y0f >= 0.0f && y0f <= (float)(H_-1)) ? 1.0f : 0.0f;
  float my1 = (y1f >= 0.0f && y1f <= (float)(H_-1)) ? 1.0f : 0.0f;

  int xc0 = (int)fminf(fmaxf(x0f, 0.0f), (float)(W_-1));
  int xc1 = (int)fminf(fmaxf(x1f, 0.0f), (float)(W_-1));
  int yc0 = (int)fminf(fmaxf(y0f, 0.0f), (float)(H_-1));
  int yc1 = (int)fminf(fmaxf(y1f, 0.0f), (float)(H_-1));

  int i00 = yc0*W_ + xc0;
  int i01 = yc0*W_ + xc1;
  int i10 = yc1*W_ + xc0;
  int i11 = yc1*W_ + xc1;

  float w00 = wx0*wy0*mx0*my0;
  float w01 = wx1*wy0*mx1*my0;
  float w10 = wx0*wy1*mx0*my1;
  float w11 = wx1*wy1*mx1*my1;

  size_t sb = (size_t)b * C_ * HW_;
  #pragma unroll
  for (int ch = 0; ch < C_; ch++) {
    const float* sc = src + sb + (size_t)ch * HW_;
    float v = sc[i00] * w00
            + sc[i01] * w01
            + sc[i10] * w10
            + sc[i11] * w11;
    out[sb + (size_t)ch * HW_ + p] = v;
  }
}

extern "C" void kernel_launch(void* const* d_in, const int* in_sizes, int n_in,
                              void* d_out, int out_size, void* d_ws, size_t ws_size,
                              hipStream_t stream) {
  const float* src   = (const float*)d_in[0];
  const float* depth = (const float*)d_in[1];
  const float* pose  = (const float*)d_in[2];
  const float* intr  = (const float*)d_in[3];
  float* out = (float*)d_out;

  int use_params = (d_ws != nullptr && ws_size >= (size_t)(B_*12*sizeof(float)))
                   ? 1 : 0;
  float* params = (float*)d_ws;

  if (use_params) {
    param_kernel<<<1, 64, 0, stream>>>(pose, intr, params);
  }
  dim3 grid(HW_ / 256, B_);
  warp_kernel<<<grid, 256, 0, stream>>>(src, depth, params, pose, intr, out,
                                        use_params);
}